// Round 1
// baseline (11.509 us; speedup 1.0000x reference)
//
#include <hip/hip_runtime.h>

// Ball query: for each query q in pc1 (8192 x 3), find the FIRST K=10 points of
// pc2 (32768 x 3) within radius 0.25, in ascending index order.
// Output (float* buffer, tuple concatenated flat):
//   [0 .. 81920)            mapping as float  (index or -1.0f), shape (8192,10)
//   [81920 .. 81920+245760) gathered points,  shape (8192,10,3) (0 for invalid)
//
// Strategy: one 64-lane wave per query. Scan pc2 in chunks of 64; __ballot the
// in-radius mask; prefix-popcount gives each hit its in-order output slot.
// Uniform early-exit once 10 hits found (typically after ~3-20 chunks since
// ~6.5% of the 32768 points are in-radius -> 10th hit at index ~150).

#define N1 8192
#define N2 32768
#define KNN 10
#define R2 0.0625f

__global__ __launch_bounds__(256) void ball_query_kernel(
    const float* __restrict__ qp,   // [N1*3]
    const float* __restrict__ pp,   // [N2*3]
    float* __restrict__ out)
{
    const int lane = threadIdx.x & 63;
    const int qid  = blockIdx.x * 4 + (threadIdx.x >> 6);

    const float qx = qp[qid * 3 + 0];
    const float qy = qp[qid * 3 + 1];
    const float qz = qp[qid * 3 + 2];

    float* __restrict__ map_out = out + (size_t)qid * KNN;
    float* __restrict__ pts_out = out + (size_t)N1 * KNN + (size_t)qid * KNN * 3;

    int count = 0;
    for (int base = 0; base < N2; base += 64) {
        const int i = base + lane;          // N2 % 64 == 0, always in bounds
        const float px = pp[i * 3 + 0];
        const float py = pp[i * 3 + 1];
        const float pz = pp[i * 3 + 2];
        const float dx = px - qx;
        const float dy = py - qy;
        const float dz = pz - qz;
        const float d2 = dx * dx + dy * dy + dz * dz;
        const bool within = d2 < R2;

        const unsigned long long m = __ballot(within);
        if (within) {
            const int rank = __popcll(m & ((1ull << lane) - 1ull));
            const int slot = count + rank;
            if (slot < KNN) {
                map_out[slot]         = (float)i;
                pts_out[slot * 3 + 0] = px;
                pts_out[slot * 3 + 1] = py;
                pts_out[slot * 3 + 2] = pz;
            }
        }
        count += __popcll(m);
        if (count >= KNN) break;            // uniform across the wave
    }

    // Fill unfilled tail slots: mapping = -1, pts = 0. Must write every call
    // (harness poisons d_out once and never re-poisons between replays).
    if (count < KNN && lane >= count && lane < KNN) {
        map_out[lane]         = -1.0f;
        pts_out[lane * 3 + 0] = 0.0f;
        pts_out[lane * 3 + 1] = 0.0f;
        pts_out[lane * 3 + 2] = 0.0f;
    }
}

extern "C" void kernel_launch(void* const* d_in, const int* in_sizes, int n_in,
                              void* d_out, int out_size, void* d_ws, size_t ws_size,
                              hipStream_t stream) {
    const float* pc1 = (const float*)d_in[0];   // (1, 8192, 3)  queries
    const float* pc2 = (const float*)d_in[1];   // (1, 32768, 3) points
    float* out = (float*)d_out;

    dim3 grid(N1 / 4);    // 4 waves per 256-thread block, one wave per query
    dim3 block(256);
    ball_query_kernel<<<grid, block, 0, stream>>>(pc1, pc2, out);
}